// Round 1
// baseline (214.500 us; speedup 1.0000x reference)
//
#include <hip/hip_runtime.h>
#include <math.h>

#define D 128
#define BCAP 8192    // per-bucket col capacity
#define SLICE 64     // per-(partition-block, bucket) slot capacity
#define PB 256       // partition blocks

typedef __attribute__((ext_vector_type(8))) short bf16x8;
typedef __attribute__((ext_vector_type(4))) float f32x4;

// ---- bf16 helpers (packed pair in a uint: low 16 = even channel) ----

__device__ inline float2 bf2f2(unsigned int u) {
    union { unsigned int i; float f; } a, b;
    a.i = u << 16;
    b.i = u & 0xffff0000u;
    return make_float2(a.f, b.f);
}

__device__ inline unsigned short f2bf(float f) {
    union { float f; unsigned int i; } u;
    u.f = f;
    unsigned int r = u.i + 0x7fffu + ((u.i >> 16) & 1u);  // RNE
    return (unsigned short)(r >> 16);
}

// ---------------- shared GEMM core (Ws already staged) ----------------
// Cb[N,128](bf16 packed) = A[N,128] @ W ; Ws bf16 [n][k] in LDS.
// 256 thr = 4 waves, 64 rows/block; wave: 16 rows x 128 cols, 4 k-steps.

__device__ __forceinline__ void gemm_core(unsigned short (*Ws)[136], int gbid,
                                          const void* __restrict__ Ain, int a_fp32,
                                          unsigned int* __restrict__ Cb, int N) {
    const int tid = threadIdx.x;
    const int wid = tid >> 6;
    const int lane = tid & 63;
    const int quad = lane >> 4;
    const int ln = lane & 15;
    const int m = gbid * 64 + wid * 16 + ln;
    const bool valid = (m < N);

    f32x4 acc[8];
#pragma unroll
    for (int c = 0; c < 8; ++c) acc[c] = (f32x4){0.f, 0.f, 0.f, 0.f};

    __syncthreads();

#pragma unroll
    for (int ks = 0; ks < 4; ++ks) {
        const int k0 = ks * 32;
        bf16x8 af;
        if (a_fp32) {
            const float* A = (const float*)Ain;
            float4 lo = make_float4(0.f, 0.f, 0.f, 0.f), hi = lo;
            if (valid) {
                lo = *(const float4*)&A[(size_t)m * 128 + k0 + quad * 8];
                hi = *(const float4*)&A[(size_t)m * 128 + k0 + quad * 8 + 4];
            }
            af[0] = (short)f2bf(lo.x); af[1] = (short)f2bf(lo.y);
            af[2] = (short)f2bf(lo.z); af[3] = (short)f2bf(lo.w);
            af[4] = (short)f2bf(hi.x); af[5] = (short)f2bf(hi.y);
            af[6] = (short)f2bf(hi.z); af[7] = (short)f2bf(hi.w);
        } else {
            const uint4* A4 = (const uint4*)Ain;
            uint4 v = valid ? A4[(size_t)m * 16 + ks * 4 + quad]
                            : make_uint4(0u, 0u, 0u, 0u);
            union { uint4 u; bf16x8 h; } cv;
            cv.u = v;
            af = cv.h;
        }
#pragma unroll
        for (int c = 0; c < 8; ++c) {
            bf16x8 bf = *(const bf16x8*)&Ws[c * 16 + ln][k0 + quad * 8];
            acc[c] = __builtin_amdgcn_mfma_f32_16x16x32_bf16(af, bf, acc[c], 0, 0, 0);
        }
    }

    const int rowbase = gbid * 64 + wid * 16 + quad * 4;
#pragma unroll
    for (int c = 0; c < 8; ++c) {
#pragma unroll
        for (int r = 0; r < 4; ++r) {
            float v = acc[c][r];
            float vn = __shfl_xor(v, 1);
            int grow = rowbase + r;
            if (!(ln & 1) && grow < N) {
                unsigned int u = (unsigned int)f2bf(v) | ((unsigned int)f2bf(vn) << 16);
                Cb[(size_t)grow * 64 + c * 8 + (ln >> 1)] = u;
            }
        }
    }
}

// ---------------- K1: partition || gemm1 (direct W1 convert) || convW2 ----

__global__ __launch_bounds__(256) void k1_all(
        const int* __restrict__ src, const int* __restrict__ dst,
        const float* __restrict__ x, const float* __restrict__ W1,
        const float* __restrict__ W2, unsigned short* __restrict__ Wt2,
        unsigned int* __restrict__ pairs, unsigned char* __restrict__ cellCnt,
        unsigned int* __restrict__ hb1, int e, int chunk, int N, int gemmBlocks) {
    __shared__ __align__(16) unsigned char smem[128 * 136 * 2];
    const int tid = threadIdx.x;
    const int bid = blockIdx.x;

    if (bid < PB) {
        int* cur = (int*)smem;
        cur[tid] = 0;
        __syncthreads();
        const int e0 = bid * chunk;
        const int e1 = min(e0 + chunk, e);
        for (int i = e0 + tid; i < e1; i += 256) {
            int d = dst[i], s = src[i];
            int b = d >> 8;
            int off = atomicAdd(&cur[b], 1);
            if (off < SLICE)
                pairs[((size_t)(bid * 256 + b)) * SLICE + off] =
                    (unsigned int)s | ((unsigned int)(d & 255) << 16);
        }
        __syncthreads();
        cellCnt[bid * 256 + tid] = (unsigned char)min(cur[tid], SLICE);
    } else if (bid < PB + gemmBlocks) {
        unsigned short (*Ws)[136] = (unsigned short(*)[136])smem;
        for (int j = 0; j < 64; ++j) {
            int idx = tid + j * 256;                 // coalesced read of W1
            Ws[idx & 127][idx >> 7] = f2bf(W1[idx]); // transposed LDS write
        }
        gemm_core(Ws, bid - PB, x, 1, hb1, N);
    } else {
        int i = (bid - PB - gemmBlocks) * 256 + tid; // 0..16383
        int k = i >> 7, n = i & 127;
        Wt2[n * 128 + k] = f2bf(W2[i]);
    }
}

// ---------------- K2: per-bucket CSR build (partB) ----------------

__global__ __launch_bounds__(256) void partB(const unsigned int* __restrict__ pairs,
                                             const unsigned char* __restrict__ cellCnt,
                                             unsigned short* __restrict__ col,
                                             unsigned int* __restrict__ meta,
                                             float* __restrict__ dinv, int n) {
    __shared__ int deg[256];
    __shared__ int sc[256];
    __shared__ int cur[256];
    const int b = blockIdx.x;
    const int tid = threadIdx.x;

    deg[tid] = 0;
    __syncthreads();

    const int c = cellCnt[tid * 256 + b];
    const unsigned int* cell = pairs + ((size_t)(tid * 256 + b)) * SLICE;
    for (int q = 0; q < c; ++q) atomicAdd(&deg[cell[q] >> 16], 1);
    __syncthreads();

    int v = deg[tid];
    sc[tid] = v;
    __syncthreads();
    for (int o = 1; o < 256; o <<= 1) {
        int t = (tid >= o) ? sc[tid - o] : 0;
        __syncthreads();
        sc[tid] += t;
        __syncthreads();
    }
    int startw = sc[tid] - v;
    cur[tid] = startw;

    int node = b * 256 + tid;
    if (node < n) {
        meta[node] = ((unsigned int)(b * BCAP + startw) << 10) | (unsigned int)v;
        dinv[node] = rsqrtf((float)(v + 1));
    }
    __syncthreads();

    for (int q = 0; q < c; ++q) {
        unsigned int p = cell[q];
        int dl = p >> 16;
        int off = atomicAdd(&cur[dl], 1);
        col[(size_t)b * BCAP + off] = (unsigned short)(p & 0xffffu);
    }
}

// ---------------- paired-neighbor agg body ----------------
// Wave split into two 32-lane halves (ph = lane>>5). Half ph handles
// neighbor 2j+ph of each pair; lane l5 holds channels 4*l5..4*l5+3 via a
// uint2 (8B) row load. One load instr = 2 rows (512B) in flight. Halves
// are merged with shfl_xor(32) at the end. meta/dinv for the node are
// preloaded by the caller (kills the per-node meta latency round).

__device__ __forceinline__ f32x4 fma4(float w, uint2 u, f32x4 a) {
    float2 f0 = bf2f2(u.x), f1 = bf2f2(u.y);
    a[0] = fmaf(w, f0.x, a[0]);
    a[1] = fmaf(w, f0.y, a[1]);
    a[2] = fmaf(w, f1.x, a[2]);
    a[3] = fmaf(w, f1.y, a[3]);
    return a;
}

__device__ __forceinline__ float2 agg_node(const unsigned int* __restrict__ hb,
                                           const unsigned short* __restrict__ col,
                                           const float* __restrict__ dinv,
                                           int node, int lane, float2 bv,
                                           unsigned int m, float di) {
    const int ph = lane >> 5;
    const int l5 = lane & 31;
    const int s0 = (int)(m >> 10);
    const int s1 = s0 + (int)(m & 1023u);

    f32x4 a0, a1, a2, a3;
    {   // self term: counted once (half 0 only); merged by the final xor-add
        uint2 su = *(const uint2*)&hb[(size_t)node * 64 + (l5 << 1)];
        float2 f0 = bf2f2(su.x), f1 = bf2f2(su.y);
        float ws = ph ? 0.f : di;
        a0 = (f32x4){ws * f0.x, ws * f0.y, ws * f1.x, ws * f1.y};
    }
    a1 = (f32x4){0.f, 0.f, 0.f, 0.f};
    a2 = a1;
    a3 = a1;

    int i = s0;
    for (; i + 16 <= s1; i += 16) {   // 16 neighbors per iteration, 8 per half
        int c0 = col[i + 0 + ph], c1 = col[i + 2 + ph];
        int c2 = col[i + 4 + ph], c3 = col[i + 6 + ph];
        int c4 = col[i + 8 + ph], c5 = col[i + 10 + ph];
        int c6 = col[i + 12 + ph], c7 = col[i + 14 + ph];
        float w0 = dinv[c0], w1 = dinv[c1], w2 = dinv[c2], w3 = dinv[c3];
        float w4 = dinv[c4], w5 = dinv[c5], w6 = dinv[c6], w7 = dinv[c7];
        uint2 u0 = *(const uint2*)&hb[(size_t)c0 * 64 + (l5 << 1)];
        uint2 u1 = *(const uint2*)&hb[(size_t)c1 * 64 + (l5 << 1)];
        uint2 u2 = *(const uint2*)&hb[(size_t)c2 * 64 + (l5 << 1)];
        uint2 u3 = *(const uint2*)&hb[(size_t)c3 * 64 + (l5 << 1)];
        uint2 u4 = *(const uint2*)&hb[(size_t)c4 * 64 + (l5 << 1)];
        uint2 u5 = *(const uint2*)&hb[(size_t)c5 * 64 + (l5 << 1)];
        uint2 u6 = *(const uint2*)&hb[(size_t)c6 * 64 + (l5 << 1)];
        uint2 u7 = *(const uint2*)&hb[(size_t)c7 * 64 + (l5 << 1)];
        a0 = fma4(w0, u0, a0); a1 = fma4(w1, u1, a1);
        a2 = fma4(w2, u2, a2); a3 = fma4(w3, u3, a3);
        a0 = fma4(w4, u4, a0); a1 = fma4(w5, u5, a1);
        a2 = fma4(w6, u6, a2); a3 = fma4(w7, u7, a3);
    }
    int rem = s1 - i;   // 0..15 remaining neighbors
    if (rem > 0) {
#pragma unroll
        for (int j = 0; j < 8; ++j) {
            int tt = 2 * j + ph;
            if (tt < rem) {     // predicated per half; masked slots untouched
                int cc = col[i + tt];
                float ww = dinv[cc];
                uint2 uu = *(const uint2*)&hb[(size_t)cc * 64 + (l5 << 1)];
                if ((j & 3) == 0)      a0 = fma4(ww, uu, a0);
                else if ((j & 3) == 1) a1 = fma4(ww, uu, a1);
                else if ((j & 3) == 2) a2 = fma4(ww, uu, a2);
                else                   a3 = fma4(ww, uu, a3);
            }
        }
    }

    f32x4 s = (a0 + a1) + (a2 + a3);
    s[0] += __shfl_xor(s[0], 32);
    s[1] += __shfl_xor(s[1], 32);
    s[2] += __shfl_xor(s[2], 32);
    s[3] += __shfl_xor(s[3], 32);

    float sx = ph ? s[2] : s[0];
    float sy = ph ? s[3] : s[1];
    float rx = fmaf(di, sx, bv.x);
    float ry = fmaf(di, sy, bv.y);
    rx = rx > 0.0f ? rx : expm1f(rx);
    ry = ry > 0.0f ? ry : expm1f(ry);
    return make_float2(rx, ry);   // channels (4*l5+2*ph, 4*l5+2*ph+1)
}

// ---------------- K3: agg1 + gemm2 fused ----------------
// Block = 16 nodes. Wave w aggregates nodes base+4w..+3 (sequential, paired-
// neighbor halves), packs post-ELU rows to bf16 in LDS. Then 16x128 @ 128x128
// MFMA against W2 (half-staged). Writes hb2.

__global__ __launch_bounds__(256, 6) void k3_agg_gemm(
        const unsigned int* __restrict__ hb1, const unsigned int* __restrict__ meta,
        const unsigned short* __restrict__ col, const float* __restrict__ dinv,
        const float* __restrict__ b1, const unsigned short* __restrict__ Wt2,
        unsigned int* __restrict__ hb2, int n) {
    __shared__ unsigned int g1s[16 * 68];                 // padded
    __shared__ __align__(16) unsigned short Ws[64][136];  // half of W2 per pass

    const int tid = threadIdx.x;
    const int wid = tid >> 6;
    const int lane = tid & 63;
    const int ph = lane >> 5;
    const int l5 = lane & 31;
    const int nodeBase = blockIdx.x * 16;
    const float2 bv = ((const float2*)b1)[(l5 << 1) + ph];

    // hoist the 4 nodes' meta/dinv (one uint4 + one float4 load)
    const int nb = nodeBase + wid * 4;
    unsigned int m4[4];
    float d4[4];
    if (nb + 3 < n) {
        const uint4 mv = *(const uint4*)&meta[nb];
        const float4 dv = *(const float4*)&dinv[nb];
        m4[0] = mv.x; m4[1] = mv.y; m4[2] = mv.z; m4[3] = mv.w;
        d4[0] = dv.x; d4[1] = dv.y; d4[2] = dv.z; d4[3] = dv.w;
    } else {
#pragma unroll
        for (int t = 0; t < 4; ++t) {
            const int nd = nb + t;
            m4[t] = (nd < n) ? meta[nd] : 0u;
            d4[t] = (nd < n) ? dinv[nd] : 0.f;
        }
    }

#pragma unroll
    for (int t = 0; t < 4; ++t) {
        const int node = nb + t;
        unsigned int packed = 0;
        if (node < n) {
            float2 r = agg_node(hb1, col, dinv, node, lane, bv, m4[t], d4[t]);
            packed = (unsigned int)f2bf(r.x) | ((unsigned int)f2bf(r.y) << 16);
        }
        g1s[(wid * 4 + t) * 68 + (l5 << 1) + ph] = packed;
    }
    __syncthreads();

    const int quad = lane >> 4;
    const int ln = lane & 15;

#pragma unroll
    for (int pass = 0; pass < 2; ++pass) {
        // stage W2 cols [pass*64, pass*64+64): 256 thr x 64 B
        {
            int nloc = tid >> 2;           // 0..63
            int kb = (tid & 3) * 32;       // shorts offset
            const uint4* g = (const uint4*)(Wt2 + (size_t)(pass * 64 + nloc) * 128 + kb);
            uint4* s = (uint4*)&Ws[nloc][kb];
            s[0] = g[0]; s[1] = g[1]; s[2] = g[2]; s[3] = g[3];
        }
        __syncthreads();

        // wave w computes col-tile c = pass*4 + w (local cols wid*16+ln)
        f32x4 acc = (f32x4){0.f, 0.f, 0.f, 0.f};
#pragma unroll
        for (int ks = 0; ks < 4; ++ks) {
            bf16x8 af = *(const bf16x8*)&g1s[ln * 68 + ks * 16 + quad * 4];
            bf16x8 bf = *(const bf16x8*)&Ws[wid * 16 + ln][ks * 32 + quad * 8];
            acc = __builtin_amdgcn_mfma_f32_16x16x32_bf16(af, bf, acc, 0, 0, 0);
        }
        const int c = pass * 4 + wid;
#pragma unroll
        for (int r = 0; r < 4; ++r) {
            float v = acc[r];
            float vn = __shfl_xor(v, 1);
            int grow = nodeBase + quad * 4 + r;
            if (!(ln & 1) && grow < n) {
                hb2[(size_t)grow * 64 + c * 8 + (ln >> 1)] =
                    (unsigned int)f2bf(v) | ((unsigned int)f2bf(vn) << 16);
            }
        }
        __syncthreads();  // protect Ws before pass-1 restage
    }
}

// ---------------- K4: final aggregation + bias + ELU (fp32 out) ----------------

__global__ __launch_bounds__(256, 6) void agg_elu(const unsigned int* __restrict__ hb,
                                                  const unsigned int* __restrict__ meta,
                                                  const unsigned short* __restrict__ col,
                                                  const float* __restrict__ dinv,
                                                  const float* __restrict__ bias,
                                                  float* __restrict__ outf, int n) {
    const int wid = threadIdx.x >> 6;
    const int lane = threadIdx.x & 63;
    const int ph = lane >> 5;
    const int l5 = lane & 31;
    const int node = blockIdx.x * 4 + wid;
    if (node >= n) return;
    const float2 bv = ((const float2*)bias)[(l5 << 1) + ph];
    const unsigned int m = meta[node];
    const float di = dinv[node];
    float2 r = agg_node(hb, col, dinv, node, lane, bv, m, di);
    ((float2*)outf)[(size_t)node * 64 + (l5 << 1) + ph] = r;
}

// ---------------- launch ----------------

extern "C" void kernel_launch(void* const* d_in, const int* in_sizes, int n_in,
                              void* d_out, int out_size, void* d_ws, size_t ws_size,
                              hipStream_t stream) {
    const float* x  = (const float*)d_in[0];
    const int*   ei = (const int*)d_in[1];
    const float* W1 = (const float*)d_in[2];
    const float* b1 = (const float*)d_in[3];
    const float* W2 = (const float*)d_in[4];
    const float* b2 = (const float*)d_in[5];
    float* out = (float*)d_out;

    const int N = in_sizes[0] / D;   // 50000 < 65536 -> u16 col ids valid
    const int E = in_sizes[1] / 2;
    const int* src = ei;
    const int* dst = ei + E;
    const int NB = (N + 255) / 256;  // buckets

    char* ws = (char*)d_ws;
    size_t off = 0;
    auto alloc = [&](size_t bytes) -> void* {
        void* p = ws + off;
        off = (off + bytes + 255) & ~(size_t)255;
        return p;
    };
    unsigned int*   pairs   = (unsigned int*)alloc((size_t)PB * 256 * SLICE * 4);
    unsigned char*  cellCnt = (unsigned char*)alloc((size_t)PB * 256);
    unsigned short* col     = (unsigned short*)alloc((size_t)NB * BCAP * 2);
    unsigned int*   meta    = (unsigned int*)alloc((size_t)N * 4);
    float*          dinv    = (float*)alloc((size_t)N * 4);
    unsigned short* Wt2     = (unsigned short*)alloc(128 * 128 * 2);
    unsigned int*   hb1     = (unsigned int*)alloc((size_t)N * 64 * 4);  // layer-1 gemm out (bf16)
    unsigned int*   hb2     = (unsigned int*)alloc((size_t)N * 64 * 4);  // layer-2 gemm out (bf16)
    (void)ws_size; (void)n_in; (void)out_size;

    const int chunk = (E + PB - 1) / PB;
    const int gemmBlocks = (N + 63) / 64;

    // K1: edge partition || hb1 = bf16(x @ W1) || Wt2 = bf16(W2^T)
    k1_all<<<PB + gemmBlocks + 64, 256, 0, stream>>>(src, dst, x, W1, W2, Wt2,
                                                     pairs, cellCnt, hb1, E, chunk,
                                                     N, gemmBlocks);
    // K2: CSR build (col, meta, dinv)
    partB<<<NB, 256, 0, stream>>>(pairs, cellCnt, col, meta, dinv, N);
    // K3: hb2 = bf16( ELU(Agg(hb1)+b1) @ W2 )
    k3_agg_gemm<<<(N + 15) / 16, 256, 0, stream>>>(hb1, meta, col, dinv, b1, Wt2, hb2, N);
    // K4: out = ELU(Agg(hb2) + b2)   [fp32]
    agg_elu<<<(N + 3) / 4, 256, 0, stream>>>(hb2, meta, col, dinv, b2, out, N);
}

// Round 2
// 201.505 us; speedup vs baseline: 1.0645x; 1.0645x over previous
//
#include <hip/hip_runtime.h>
#include <math.h>

#define D 128
#define BCAP 8192    // per-bucket col capacity
#define SLICE 64     // per-(partition-block, bucket) slot capacity
#define PB 256       // partition blocks

typedef __attribute__((ext_vector_type(8))) short bf16x8;
typedef __attribute__((ext_vector_type(4))) float f32x4;

// ---- bf16 helpers (packed pair in a uint: low 16 = even channel) ----

__device__ inline float2 bf2f2(unsigned int u) {
    union { unsigned int i; float f; } a, b;
    a.i = u << 16;
    b.i = u & 0xffff0000u;
    return make_float2(a.f, b.f);
}

__device__ inline unsigned short f2bf(float f) {
    union { float f; unsigned int i; } u;
    u.f = f;
    unsigned int r = u.i + 0x7fffu + ((u.i >> 16) & 1u);  // RNE
    return (unsigned short)(r >> 16);
}

// ---------------- shared GEMM core (Ws already staged) ----------------
// Cb[N,128](bf16 packed) = A[N,128] @ W ; Ws bf16 [n][k] in LDS.
// 256 thr = 4 waves, 64 rows/block; wave: 16 rows x 128 cols, 4 k-steps.

__device__ __forceinline__ void gemm_core(unsigned short (*Ws)[136], int gbid,
                                          const void* __restrict__ Ain, int a_fp32,
                                          unsigned int* __restrict__ Cb, int N) {
    const int tid = threadIdx.x;
    const int wid = tid >> 6;
    const int lane = tid & 63;
    const int quad = lane >> 4;
    const int ln = lane & 15;
    const int m = gbid * 64 + wid * 16 + ln;
    const bool valid = (m < N);

    f32x4 acc[8];
#pragma unroll
    for (int c = 0; c < 8; ++c) acc[c] = (f32x4){0.f, 0.f, 0.f, 0.f};

    __syncthreads();

#pragma unroll
    for (int ks = 0; ks < 4; ++ks) {
        const int k0 = ks * 32;
        bf16x8 af;
        if (a_fp32) {
            const float* A = (const float*)Ain;
            float4 lo = make_float4(0.f, 0.f, 0.f, 0.f), hi = lo;
            if (valid) {
                lo = *(const float4*)&A[(size_t)m * 128 + k0 + quad * 8];
                hi = *(const float4*)&A[(size_t)m * 128 + k0 + quad * 8 + 4];
            }
            af[0] = (short)f2bf(lo.x); af[1] = (short)f2bf(lo.y);
            af[2] = (short)f2bf(lo.z); af[3] = (short)f2bf(lo.w);
            af[4] = (short)f2bf(hi.x); af[5] = (short)f2bf(hi.y);
            af[6] = (short)f2bf(hi.z); af[7] = (short)f2bf(hi.w);
        } else {
            const uint4* A4 = (const uint4*)Ain;
            uint4 v = valid ? A4[(size_t)m * 16 + ks * 4 + quad]
                            : make_uint4(0u, 0u, 0u, 0u);
            union { uint4 u; bf16x8 h; } cv;
            cv.u = v;
            af = cv.h;
        }
#pragma unroll
        for (int c = 0; c < 8; ++c) {
            bf16x8 bf = *(const bf16x8*)&Ws[c * 16 + ln][k0 + quad * 8];
            acc[c] = __builtin_amdgcn_mfma_f32_16x16x32_bf16(af, bf, acc[c], 0, 0, 0);
        }
    }

    const int rowbase = gbid * 64 + wid * 16 + quad * 4;
#pragma unroll
    for (int c = 0; c < 8; ++c) {
#pragma unroll
        for (int r = 0; r < 4; ++r) {
            float v = acc[c][r];
            float vn = __shfl_xor(v, 1);
            int grow = rowbase + r;
            if (!(ln & 1) && grow < N) {
                unsigned int u = (unsigned int)f2bf(v) | ((unsigned int)f2bf(vn) << 16);
                Cb[(size_t)grow * 64 + c * 8 + (ln >> 1)] = u;
            }
        }
    }
}

// ---------------- K1: partition || gemm1 (direct W1 convert) || convW2 ----

__global__ __launch_bounds__(256) void k1_all(
        const int* __restrict__ src, const int* __restrict__ dst,
        const float* __restrict__ x, const float* __restrict__ W1,
        const float* __restrict__ W2, unsigned short* __restrict__ Wt2,
        unsigned int* __restrict__ pairs, unsigned char* __restrict__ cellCnt,
        unsigned int* __restrict__ hb1, int e, int chunk, int N, int gemmBlocks) {
    __shared__ __align__(16) unsigned char smem[128 * 136 * 2];
    const int tid = threadIdx.x;
    const int bid = blockIdx.x;

    if (bid < PB) {
        int* cur = (int*)smem;
        cur[tid] = 0;
        __syncthreads();
        const int e0 = bid * chunk;
        const int e1 = min(e0 + chunk, e);
        for (int i = e0 + tid; i < e1; i += 256) {
            int d = dst[i], s = src[i];
            int b = d >> 8;
            int off = atomicAdd(&cur[b], 1);
            if (off < SLICE)
                pairs[((size_t)(bid * 256 + b)) * SLICE + off] =
                    (unsigned int)s | ((unsigned int)(d & 255) << 16);
        }
        __syncthreads();
        cellCnt[bid * 256 + tid] = (unsigned char)min(cur[tid], SLICE);
    } else if (bid < PB + gemmBlocks) {
        unsigned short (*Ws)[136] = (unsigned short(*)[136])smem;
        for (int j = 0; j < 64; ++j) {
            int idx = tid + j * 256;                 // coalesced read of W1
            Ws[idx & 127][idx >> 7] = f2bf(W1[idx]); // transposed LDS write
        }
        gemm_core(Ws, bid - PB, x, 1, hb1, N);
    } else {
        int i = (bid - PB - gemmBlocks) * 256 + tid; // 0..16383
        int k = i >> 7, n = i & 127;
        Wt2[n * 128 + k] = f2bf(W2[i]);
    }
}

// ---------------- K2: per-bucket CSR build (partB) ----------------

__global__ __launch_bounds__(256) void partB(const unsigned int* __restrict__ pairs,
                                             const unsigned char* __restrict__ cellCnt,
                                             unsigned short* __restrict__ col,
                                             unsigned int* __restrict__ meta,
                                             float* __restrict__ dinv, int n) {
    __shared__ int deg[256];
    __shared__ int sc[256];
    __shared__ int cur[256];
    const int b = blockIdx.x;
    const int tid = threadIdx.x;

    deg[tid] = 0;
    __syncthreads();

    const int c = cellCnt[tid * 256 + b];
    const unsigned int* cell = pairs + ((size_t)(tid * 256 + b)) * SLICE;
    for (int q = 0; q < c; ++q) atomicAdd(&deg[cell[q] >> 16], 1);
    __syncthreads();

    int v = deg[tid];
    sc[tid] = v;
    __syncthreads();
    for (int o = 1; o < 256; o <<= 1) {
        int t = (tid >= o) ? sc[tid - o] : 0;
        __syncthreads();
        sc[tid] += t;
        __syncthreads();
    }
    int startw = sc[tid] - v;
    cur[tid] = startw;

    int node = b * 256 + tid;
    if (node < n) {
        meta[node] = ((unsigned int)(b * BCAP + startw) << 10) | (unsigned int)v;
        dinv[node] = rsqrtf((float)(v + 1));
    }
    __syncthreads();

    for (int q = 0; q < c; ++q) {
        unsigned int p = cell[q];
        int dl = p >> 16;
        int off = atomicAdd(&cur[dl], 1);
        col[(size_t)b * BCAP + off] = (unsigned short)(p & 0xffffu);
    }
}

// ---------------- agg body (one node, one wave-lane's 2 channels) ----------
// Round-0 proven form: full 64-lane wave per node, 8 rows in flight per
// batch, simple serial tail. meta/dinv preloaded by the caller.

__device__ __forceinline__ float2 agg_node(const unsigned int* __restrict__ hb,
                                           const unsigned short* __restrict__ col,
                                           const float* __restrict__ dinv,
                                           int node, int lane, float2 bv,
                                           unsigned int m, float di) {
    float2 self = bf2f2(hb[(size_t)node * 64 + lane]);
    float2 a0 = make_float2(di * self.x, di * self.y);
    float2 a1 = make_float2(0.f, 0.f), a2 = make_float2(0.f, 0.f),
           a3 = make_float2(0.f, 0.f), a4 = make_float2(0.f, 0.f),
           a5 = make_float2(0.f, 0.f), a6 = make_float2(0.f, 0.f),
           a7 = make_float2(0.f, 0.f);

    const int s0 = (int)(m >> 10);
    const int s1 = s0 + (int)(m & 1023u);
    int i = s0;
    for (; i + 8 <= s1; i += 8) {
        int c0 = col[i + 0], c1 = col[i + 1], c2 = col[i + 2], c3 = col[i + 3];
        int c4 = col[i + 4], c5 = col[i + 5], c6 = col[i + 6], c7 = col[i + 7];
        float w0 = dinv[c0], w1 = dinv[c1], w2 = dinv[c2], w3 = dinv[c3];
        float w4 = dinv[c4], w5 = dinv[c5], w6 = dinv[c6], w7 = dinv[c7];
        unsigned int u0 = hb[(size_t)c0 * 64 + lane];
        unsigned int u1 = hb[(size_t)c1 * 64 + lane];
        unsigned int u2 = hb[(size_t)c2 * 64 + lane];
        unsigned int u3 = hb[(size_t)c3 * 64 + lane];
        unsigned int u4 = hb[(size_t)c4 * 64 + lane];
        unsigned int u5 = hb[(size_t)c5 * 64 + lane];
        unsigned int u6 = hb[(size_t)c6 * 64 + lane];
        unsigned int u7 = hb[(size_t)c7 * 64 + lane];
        float2 v0 = bf2f2(u0), v1 = bf2f2(u1), v2 = bf2f2(u2), v3 = bf2f2(u3);
        float2 v4 = bf2f2(u4), v5 = bf2f2(u5), v6 = bf2f2(u6), v7 = bf2f2(u7);
        a0.x = fmaf(w0, v0.x, a0.x); a0.y = fmaf(w0, v0.y, a0.y);
        a1.x = fmaf(w1, v1.x, a1.x); a1.y = fmaf(w1, v1.y, a1.y);
        a2.x = fmaf(w2, v2.x, a2.x); a2.y = fmaf(w2, v2.y, a2.y);
        a3.x = fmaf(w3, v3.x, a3.x); a3.y = fmaf(w3, v3.y, a3.y);
        a4.x = fmaf(w4, v4.x, a4.x); a4.y = fmaf(w4, v4.y, a4.y);
        a5.x = fmaf(w5, v5.x, a5.x); a5.y = fmaf(w5, v5.y, a5.y);
        a6.x = fmaf(w6, v6.x, a6.x); a6.y = fmaf(w6, v6.y, a6.y);
        a7.x = fmaf(w7, v7.x, a7.x); a7.y = fmaf(w7, v7.y, a7.y);
    }
    for (; i < s1; ++i) {
        int c = col[i];
        float ww = dinv[c];
        float2 v = bf2f2(hb[(size_t)c * 64 + lane]);
        a0.x = fmaf(ww, v.x, a0.x); a0.y = fmaf(ww, v.y, a0.y);
    }

    float sx = (a0.x + a1.x) + (a2.x + a3.x) + (a4.x + a5.x) + (a6.x + a7.x);
    float sy = (a0.y + a1.y) + (a2.y + a3.y) + (a4.y + a5.y) + (a6.y + a7.y);
    float rx = fmaf(di, sx, bv.x);
    float ry = fmaf(di, sy, bv.y);
    rx = rx > 0.0f ? rx : expm1f(rx);
    ry = ry > 0.0f ? ry : expm1f(ry);
    return make_float2(rx, ry);
}

// ---------------- K3: agg1 + gemm2 fused, ONE NODE PER WAVE ----------------
// Block = 1024 thr = 16 waves = 16 nodes (one MFMA row-tile). Each wave
// aggregates exactly one node (dependency chain: meta -> col -> hb, ~3
// rounds vs 12 for 4-nodes-serial), packs its post-ELU row to bf16 in LDS.
// Full W2 staged once (no per-pass restage); waves 0..7 then compute the
// 8 col-tiles of the 16x128 @ 128x128 MFMA product. LDS 38.3 KB -> 2
// blocks/CU (32 waves = 100% occupancy cap).

__global__ __launch_bounds__(1024, 8) void k3_agg_gemm(
        const unsigned int* __restrict__ hb1, const unsigned int* __restrict__ meta,
        const unsigned short* __restrict__ col, const float* __restrict__ dinv,
        const float* __restrict__ b1, const unsigned short* __restrict__ Wt2,
        unsigned int* __restrict__ hb2, int n) {
    __shared__ unsigned int g1s[16 * 68];                 // padded rows
    __shared__ __align__(16) unsigned short Ws[128][136]; // full W2 (bf16, [n][k])

    const int tid = threadIdx.x;
    const int wid = tid >> 6;        // 0..15 = node slot
    const int lane = tid & 63;
    const int nodeBase = blockIdx.x * 16;
    const int node = nodeBase + wid;

    // stage full W2: 1024 thr, 8 thr/row, 2x uint4 (16 shorts) each
    {
        const int nloc = tid >> 3;        // 0..127 (output col)
        const int kb = (tid & 7) * 16;    // shorts offset
        const uint4* g = (const uint4*)(Wt2 + (size_t)nloc * 128 + kb);
        uint4* s = (uint4*)&Ws[nloc][kb];
        s[0] = g[0];
        s[1] = g[1];
    }

    // aggregate this wave's node
    const float2 bv = ((const float2*)b1)[lane];
    unsigned int packed = 0;
    if (node < n) {
        const unsigned int m = meta[node];
        const float di = dinv[node];
        float2 r = agg_node(hb1, col, dinv, node, lane, bv, m, di);
        packed = (unsigned int)f2bf(r.x) | ((unsigned int)f2bf(r.y) << 16);
    }
    g1s[wid * 68 + lane] = packed;
    __syncthreads();

    // GEMM: wave w (0..7) computes col-tile c = w (cols c*16 .. c*16+15)
    if (wid < 8) {
        const int quad = lane >> 4;
        const int ln = lane & 15;
        f32x4 acc = (f32x4){0.f, 0.f, 0.f, 0.f};
#pragma unroll
        for (int ks = 0; ks < 4; ++ks) {
            bf16x8 af = *(const bf16x8*)&g1s[ln * 68 + ks * 16 + quad * 4];
            bf16x8 bf = *(const bf16x8*)&Ws[wid * 16 + ln][ks * 32 + quad * 8];
            acc = __builtin_amdgcn_mfma_f32_16x16x32_bf16(af, bf, acc, 0, 0, 0);
        }
#pragma unroll
        for (int r = 0; r < 4; ++r) {
            float v = acc[r];
            float vn = __shfl_xor(v, 1);
            int grow = nodeBase + quad * 4 + r;
            if (!(ln & 1) && grow < n) {
                hb2[(size_t)grow * 64 + wid * 8 + (ln >> 1)] =
                    (unsigned int)f2bf(v) | ((unsigned int)f2bf(vn) << 16);
            }
        }
    }
}

// ---------------- K4: final aggregation + bias + ELU (fp32 out) ----------------

__global__ __launch_bounds__(256) void agg_elu(const unsigned int* __restrict__ hb,
                                               const unsigned int* __restrict__ meta,
                                               const unsigned short* __restrict__ col,
                                               const float* __restrict__ dinv,
                                               const float* __restrict__ bias,
                                               float* __restrict__ outf, int n) {
    const int wid = threadIdx.x >> 6;
    const int lane = threadIdx.x & 63;
    const int node = blockIdx.x * 4 + wid;
    if (node >= n) return;
    const float2 bv = ((const float2*)bias)[lane];
    const unsigned int m = meta[node];
    const float di = dinv[node];
    float2 r = agg_node(hb, col, dinv, node, lane, bv, m, di);
    ((float2*)outf)[(size_t)node * 64 + lane] = r;
}

// ---------------- launch ----------------

extern "C" void kernel_launch(void* const* d_in, const int* in_sizes, int n_in,
                              void* d_out, int out_size, void* d_ws, size_t ws_size,
                              hipStream_t stream) {
    const float* x  = (const float*)d_in[0];
    const int*   ei = (const int*)d_in[1];
    const float* W1 = (const float*)d_in[2];
    const float* b1 = (const float*)d_in[3];
    const float* W2 = (const float*)d_in[4];
    const float* b2 = (const float*)d_in[5];
    float* out = (float*)d_out;

    const int N = in_sizes[0] / D;   // 50000 < 65536 -> u16 col ids valid
    const int E = in_sizes[1] / 2;
    const int* src = ei;
    const int* dst = ei + E;
    const int NB = (N + 255) / 256;  // buckets

    char* ws = (char*)d_ws;
    size_t off = 0;
    auto alloc = [&](size_t bytes) -> void* {
        void* p = ws + off;
        off = (off + bytes + 255) & ~(size_t)255;
        return p;
    };
    unsigned int*   pairs   = (unsigned int*)alloc((size_t)PB * 256 * SLICE * 4);
    unsigned char*  cellCnt = (unsigned char*)alloc((size_t)PB * 256);
    unsigned short* col     = (unsigned short*)alloc((size_t)NB * BCAP * 2);
    unsigned int*   meta    = (unsigned int*)alloc((size_t)N * 4);
    float*          dinv    = (float*)alloc((size_t)N * 4);
    unsigned short* Wt2     = (unsigned short*)alloc(128 * 128 * 2);
    unsigned int*   hb1     = (unsigned int*)alloc((size_t)N * 64 * 4);  // layer-1 gemm out (bf16)
    unsigned int*   hb2     = (unsigned int*)alloc((size_t)N * 64 * 4);  // layer-2 gemm out (bf16)
    (void)ws_size; (void)n_in; (void)out_size;

    const int chunk = (E + PB - 1) / PB;
    const int gemmBlocks = (N + 63) / 64;

    // K1: edge partition || hb1 = bf16(x @ W1) || Wt2 = bf16(W2^T)
    k1_all<<<PB + gemmBlocks + 64, 256, 0, stream>>>(src, dst, x, W1, W2, Wt2,
                                                     pairs, cellCnt, hb1, E, chunk,
                                                     N, gemmBlocks);
    // K2: CSR build (col, meta, dinv)
    partB<<<NB, 256, 0, stream>>>(pairs, cellCnt, col, meta, dinv, N);
    // K3: hb2 = bf16( ELU(Agg(hb1)+b1) @ W2 )  [1 node per wave]
    k3_agg_gemm<<<(N + 15) / 16, 1024, 0, stream>>>(hb1, meta, col, dinv, b1, Wt2, hb2, N);
    // K4: out = ELU(Agg(hb2) + b2)   [fp32]
    agg_elu<<<(N + 3) / 4, 256, 0, stream>>>(hb2, meta, col, dinv, b2, out, N);
}